// Round 1
// baseline (1069.048 us; speedup 1.0000x reference)
//
#include <hip/hip_runtime.h>

#define IN_CH 64
#define HC 128          // HEADS * OUT_CH
#define HEADS 8
#define OUT_CH 16
#define NEG 0.2f
#define NPB 2           // nodes per block in proj kernel

// monotonic float -> uint key (order-preserving) for atomicMax on floats
__device__ __forceinline__ unsigned int fkey(float f) {
    unsigned int u = __float_as_uint(f);
    return (u & 0x80000000u) ? ~u : (u | 0x80000000u);
}
__device__ __forceinline__ float kinv(unsigned int k) {
    unsigned int u = (k & 0x80000000u) ? (k & 0x7fffffffu) : ~k;
    return __uint_as_float(u);
}

__device__ __forceinline__ float lrelu(float x) {
    return x >= 0.f ? x : NEG * x;
}

// h = x @ W  [N,128]; a_src/a_dst [N,8] fused via 16-lane shuffle reduce
__global__ __launch_bounds__(256) void proj_kernel(
    const float* __restrict__ x, const float* __restrict__ W,
    const float* __restrict__ att_src, const float* __restrict__ att_dst,
    float* __restrict__ h, float* __restrict__ asrc, float* __restrict__ adst,
    int n)
{
    __shared__ float sW[IN_CH * HC];
    __shared__ float sx[NPB * IN_CH];
    int tid = threadIdx.x;

    const float4* W4 = (const float4*)W;
    float4* sW4 = (float4*)sW;
    #pragma unroll
    for (int i = tid; i < IN_CH * HC / 4; i += 256) sW4[i] = W4[i];

    int node0 = blockIdx.x * NPB;
    for (int i = tid; i < NPB * IN_CH; i += 256) {
        int nn = node0 + i / IN_CH;
        sx[i] = (nn < n) ? x[(long long)nn * IN_CH + (i % IN_CH)] : 0.f;
    }
    __syncthreads();

    int local = tid / HC;       // node within block
    int col   = tid % HC;       // output column 0..127
    int node  = node0 + local;
    if (node >= n) return;

    float acc = 0.f;
    #pragma unroll
    for (int k = 0; k < IN_CH; ++k)
        acc = fmaf(sx[local * IN_CH + k], sW[k * HC + col], acc);
    h[(long long)node * HC + col] = acc;

    int head = col >> 4, c = col & 15;
    float vs = acc * att_src[head * OUT_CH + c];
    float vd = acc * att_dst[head * OUT_CH + c];
    #pragma unroll
    for (int m = 8; m >= 1; m >>= 1) {
        vs += __shfl_xor(vs, m, 64);
        vd += __shfl_xor(vd, m, 64);
    }
    if (c == 0) {
        asrc[node * HEADS + head] = vs;
        adst[node * HEADS + head] = vd;
    }
}

// pass 1: segment max of leaky_relu(a_src[src]+a_dst[dst]) into amax key
__global__ __launch_bounds__(256) void edge_max_kernel(
    const int* __restrict__ ei, int E, int n,
    const float* __restrict__ asrc, const float* __restrict__ adst,
    unsigned int* __restrict__ amax_key)
{
    long long t = (long long)blockIdx.x * blockDim.x + threadIdx.x;
    long long total = (long long)(E + n) * HEADS;
    if (t >= total) return;
    int e  = (int)(t >> 3);
    int hd = (int)(t & 7);
    int s, d;
    if (e < E) { s = ei[e]; d = ei[E + e]; } else { s = d = e - E; }
    float alpha = lrelu(asrc[s * HEADS + hd] + adst[d * HEADS + hd]);
    atomicMax(&amax_key[d * HEADS + hd], fkey(alpha));
}

// pass 2: denom = segment sum of exp(alpha - amax[dst])
__global__ __launch_bounds__(256) void edge_sum_kernel(
    const int* __restrict__ ei, int E, int n,
    const float* __restrict__ asrc, const float* __restrict__ adst,
    const unsigned int* __restrict__ amax_key, float* __restrict__ denom)
{
    long long t = (long long)blockIdx.x * blockDim.x + threadIdx.x;
    long long total = (long long)(E + n) * HEADS;
    if (t >= total) return;
    int e  = (int)(t >> 3);
    int hd = (int)(t & 7);
    int s, d;
    if (e < E) { s = ei[e]; d = ei[E + e]; } else { s = d = e - E; }
    float alpha = lrelu(asrc[s * HEADS + hd] + adst[d * HEADS + hd]);
    float ex = __expf(alpha - kinv(amax_key[d * HEADS + hd]));
    atomicAdd(&denom[d * HEADS + hd], ex);
}

// pass 3: out[dst, col] += attn * h[src, col]
__global__ __launch_bounds__(256) void edge_agg_kernel(
    const int* __restrict__ ei, int E, int n,
    const float* __restrict__ asrc, const float* __restrict__ adst,
    const unsigned int* __restrict__ amax_key, const float* __restrict__ denom,
    const float* __restrict__ h, float* __restrict__ out)
{
    long long t = (long long)blockIdx.x * blockDim.x + threadIdx.x;
    long long total = (long long)(E + n) * HC;
    if (t >= total) return;
    int e   = (int)(t >> 7);
    int col = (int)(t & 127);
    int hd  = col >> 4;
    int s, d;
    if (e < E) { s = ei[e]; d = ei[E + e]; } else { s = d = e - E; }
    float alpha = lrelu(asrc[s * HEADS + hd] + adst[d * HEADS + hd]);
    float attn = __expf(alpha - kinv(amax_key[d * HEADS + hd]))
               / (denom[d * HEADS + hd] + 1e-16f);
    atomicAdd(&out[(long long)d * HC + col],
              attn * h[(long long)s * HC + col]);
}

// out = relu(out + bias)
__global__ __launch_bounds__(256) void finalize_kernel(
    float* __restrict__ out, const float* __restrict__ bias, long long total)
{
    long long t = (long long)blockIdx.x * blockDim.x + threadIdx.x;
    if (t >= total) return;
    out[t] = fmaxf(out[t] + bias[t & (HC - 1)], 0.f);
}

extern "C" void kernel_launch(void* const* d_in, const int* in_sizes, int n_in,
                              void* d_out, int out_size, void* d_ws, size_t ws_size,
                              hipStream_t stream) {
    const float* x       = (const float*)d_in[0];
    const float* W       = (const float*)d_in[1];
    const float* att_src = (const float*)d_in[2];
    const float* att_dst = (const float*)d_in[3];
    const float* bias    = (const float*)d_in[4];
    const int*   ei      = (const int*)d_in[5];

    int n = in_sizes[0] / IN_CH;        // 100000
    int E = in_sizes[5] / 2;            // 1600000
    float* out = (float*)d_out;

    // workspace layout
    char* ws = (char*)d_ws;
    float*        h        = (float*)ws;                         ws += (size_t)n * HC * 4;
    float*        asrc     = (float*)ws;                         ws += (size_t)n * HEADS * 4;
    float*        adst     = (float*)ws;                         ws += (size_t)n * HEADS * 4;
    unsigned int* amax_key = (unsigned int*)ws;                  ws += (size_t)n * HEADS * 4;
    float*        denom    = (float*)ws;                         ws += (size_t)n * HEADS * 4;

    hipMemsetAsync(d_out, 0, (size_t)out_size * 4, stream);
    hipMemsetAsync(amax_key, 0, (size_t)n * HEADS * 4, stream);  // key 0 == -inf-ish
    hipMemsetAsync(denom, 0, (size_t)n * HEADS * 4, stream);

    // projection + logits
    int nblk = (n + NPB - 1) / NPB;
    proj_kernel<<<nblk, 256, 0, stream>>>(x, W, att_src, att_dst, h, asrc, adst, n);

    long long eh_total = (long long)(E + n) * HEADS;
    int eh_blocks = (int)((eh_total + 255) / 256);
    edge_max_kernel<<<eh_blocks, 256, 0, stream>>>(ei, E, n, asrc, adst, amax_key);
    edge_sum_kernel<<<eh_blocks, 256, 0, stream>>>(ei, E, n, asrc, adst, amax_key, denom);

    long long agg_total = (long long)(E + n) * HC;
    int agg_blocks = (int)((agg_total + 255) / 256);
    edge_agg_kernel<<<agg_blocks, 256, 0, stream>>>(ei, E, n, asrc, adst, amax_key,
                                                    denom, h, out);

    long long fin_total = (long long)n * HC;
    int fin_blocks = (int)((fin_total + 255) / 256);
    finalize_kernel<<<fin_blocks, 256, 0, stream>>>(out, bias, fin_total);
}

// Round 2
// 523.723 us; speedup vs baseline: 2.0412x; 2.0412x over previous
//
#include <hip/hip_runtime.h>

#define IN_CH 64
#define HC 128          // HEADS * OUT_CH
#define HEADS 8
#define OUT_CH 16
#define NEG 0.2f
#define NPB 2           // nodes per block in proj kernel

__device__ __forceinline__ float lrelu(float x) {
    return x >= 0.f ? x : NEG * x;
}

// h = x @ W  [N,128]; a_src/a_dst [N,8] fused via 16-lane shuffle reduce
__global__ __launch_bounds__(256) void proj_kernel(
    const float* __restrict__ x, const float* __restrict__ W,
    const float* __restrict__ att_src, const float* __restrict__ att_dst,
    float* __restrict__ h, float* __restrict__ asrc, float* __restrict__ adst,
    int n)
{
    __shared__ float sW[IN_CH * HC];
    __shared__ float sx[NPB * IN_CH];
    int tid = threadIdx.x;

    const float4* W4 = (const float4*)W;
    float4* sW4 = (float4*)sW;
    #pragma unroll
    for (int i = tid; i < IN_CH * HC / 4; i += 256) sW4[i] = W4[i];

    int node0 = blockIdx.x * NPB;
    for (int i = tid; i < NPB * IN_CH; i += 256) {
        int nn = node0 + i / IN_CH;
        sx[i] = (nn < n) ? x[(long long)nn * IN_CH + (i % IN_CH)] : 0.f;
    }
    __syncthreads();

    int local = tid / HC;       // node within block
    int col   = tid % HC;       // output column 0..127
    int node  = node0 + local;
    if (node >= n) return;

    float acc = 0.f;
    #pragma unroll
    for (int k = 0; k < IN_CH; ++k)
        acc = fmaf(sx[local * IN_CH + k], sW[k * HC + col], acc);
    h[(long long)node * HC + col] = acc;

    int head = col >> 4, c = col & 15;
    float vs = acc * att_src[head * OUT_CH + c];
    float vd = acc * att_dst[head * OUT_CH + c];
    #pragma unroll
    for (int m = 8; m >= 1; m >>= 1) {
        vs += __shfl_xor(vs, m, 64);
        vd += __shfl_xor(vd, m, 64);
    }
    if (c == 0) {
        asrc[node * HEADS + head] = vs;
        adst[node * HEADS + head] = vd;
    }
}

// ---- CSR build ----

__global__ __launch_bounds__(256) void count_kernel(
    const int* __restrict__ ei, int E, int* __restrict__ deg)
{
    int t = blockIdx.x * 256 + threadIdx.x;
    if (t < E) atomicAdd(&deg[ei[E + t]], 1);
}

// block-level scan: 1024 elems/block (4/thread), exclusive within chunk
__global__ __launch_bounds__(256) void scan1_kernel(
    const int* __restrict__ deg, int* __restrict__ row,
    int* __restrict__ bsums, int n)
{
    __shared__ int ts[256];
    int b = blockIdx.x, t = threadIdx.x;
    int base = b * 1024 + t * 4;
    int v0 = (base + 0 < n) ? deg[base + 0] : 0;
    int v1 = (base + 1 < n) ? deg[base + 1] : 0;
    int v2 = (base + 2 < n) ? deg[base + 2] : 0;
    int v3 = (base + 3 < n) ? deg[base + 3] : 0;
    int s = v0 + v1 + v2 + v3;
    ts[t] = s;
    __syncthreads();
    for (int off = 1; off < 256; off <<= 1) {
        int x = (t >= off) ? ts[t - off] : 0;
        __syncthreads();
        ts[t] += x;
        __syncthreads();
    }
    if (t == 255) bsums[b] = ts[255];
    int run = ts[t] - s;   // exclusive prefix for this thread's 4 items
    if (base + 0 < n) row[base + 0] = run; run += v0;
    if (base + 1 < n) row[base + 1] = run; run += v1;
    if (base + 2 < n) row[base + 2] = run; run += v2;
    if (base + 3 < n) row[base + 3] = run;
}

__global__ __launch_bounds__(256) void scan2_kernel(int* bsums, int nb)
{
    __shared__ int ts[256];
    int t = threadIdx.x;
    int v = (t < nb) ? bsums[t] : 0;
    ts[t] = v;
    __syncthreads();
    for (int off = 1; off < 256; off <<= 1) {
        int x = (t >= off) ? ts[t - off] : 0;
        __syncthreads();
        ts[t] += x;
        __syncthreads();
    }
    if (t < nb) bsums[t] = ts[t] - v;   // exclusive
}

__global__ __launch_bounds__(256) void scan3_kernel(
    int* __restrict__ row, const int* __restrict__ bsums, int n)
{
    int b = blockIdx.x;
    int base = b * 1024 + threadIdx.x * 4;
    int add = bsums[b];
    #pragma unroll
    for (int i = 0; i < 4; ++i)
        if (base + i < n) row[base + i] += add;
}

// scatter edges into CSR slots; row[] doubles as cursor (after this,
// row[d] == original row[d+1])
__global__ __launch_bounds__(256) void scatter_kernel(
    const int* __restrict__ ei, int E,
    int* __restrict__ row, int* __restrict__ csr)
{
    int t = blockIdx.x * 256 + threadIdx.x;
    if (t < E) {
        int s = ei[t], d = ei[E + t];
        int pos = atomicAdd(&row[d], 1);
        csr[pos] = s;
    }
}

// ---- fused softmax + aggregation: one wave per dst node ----
__global__ __launch_bounds__(256) void agg_kernel(
    const int* __restrict__ csr, const int* __restrict__ row,
    const float* __restrict__ asrc, const float* __restrict__ adst,
    const float* __restrict__ h, const float* __restrict__ bias,
    float* __restrict__ out, int n)
{
    int wave = threadIdx.x >> 6;
    int lane = threadIdx.x & 63;
    int d = blockIdx.x * 4 + wave;
    if (d >= n) return;

    int hA = lane & 7;    // head this lane computes the logit for
    int hO = lane >> 3;   // head owning this lane's output cols (2l, 2l+1)

    int end   = row[d];                 // = original row[d+1] after scatter
    int start = d ? row[d - 1] : 0;     // = original row[d]

    float adstv = adst[d * HEADS + hA];
    const float2* h2 = (const float2*)h;

    // self loop first
    float alpha = lrelu(asrc[d * HEADS + hA] + adstv);
    float aown  = __shfl(alpha, hO);
    float m = aown, denom = 1.f;
    float2 v = h2[(long long)d * 64 + lane];
    float accx = v.x, accy = v.y;

    for (int j = start; j < end; ++j) {
        int s = csr[j];
        alpha = lrelu(asrc[s * HEADS + hA] + adstv);
        aown  = __shfl(alpha, hO);
        float mn = fmaxf(m, aown);
        float sc = __expf(m - mn);
        float p  = __expf(aown - mn);
        v = h2[(long long)s * 64 + lane];
        denom = denom * sc + p;
        accx  = accx * sc + p * v.x;
        accy  = accy * sc + p * v.y;
        m = mn;
    }

    float inv = 1.f / (denom + 1e-16f);
    const float2* b2 = (const float2*)bias;
    float2 bb = b2[lane];
    float2 o;
    o.x = fmaxf(accx * inv + bb.x, 0.f);
    o.y = fmaxf(accy * inv + bb.y, 0.f);
    ((float2*)out)[(long long)d * 64 + lane] = o;
}

extern "C" void kernel_launch(void* const* d_in, const int* in_sizes, int n_in,
                              void* d_out, int out_size, void* d_ws, size_t ws_size,
                              hipStream_t stream) {
    const float* x       = (const float*)d_in[0];
    const float* W       = (const float*)d_in[1];
    const float* att_src = (const float*)d_in[2];
    const float* att_dst = (const float*)d_in[3];
    const float* bias    = (const float*)d_in[4];
    const int*   ei      = (const int*)d_in[5];

    int n = in_sizes[0] / IN_CH;        // 100000
    int E = in_sizes[5] / 2;            // 1600000
    float* out = (float*)d_out;

    // workspace layout
    char* ws = (char*)d_ws;
    float* h    = (float*)ws;  ws += (size_t)n * HC * 4;        // 51.2 MB
    float* asrc = (float*)ws;  ws += (size_t)n * HEADS * 4;     // 3.2 MB
    float* adst = (float*)ws;  ws += (size_t)n * HEADS * 4;     // 3.2 MB
    int*   csr  = (int*)ws;    ws += (size_t)E * 4;             // 6.4 MB
    int*   row  = (int*)ws;    ws += (size_t)(n + 1) * 4;       // 0.4 MB
    int*   bsums= (int*)ws;    ws += 1024;
    int*   deg  = csr;  // deg only alive until scan1; csr written later

    int nb = (n + 1023) / 1024;   // 98 (<=256)

    hipMemsetAsync(deg, 0, (size_t)n * 4, stream);

    int nblk = (n + NPB - 1) / NPB;
    proj_kernel<<<nblk, 256, 0, stream>>>(x, W, att_src, att_dst, h, asrc, adst, n);

    int eblk = (E + 255) / 256;
    count_kernel<<<eblk, 256, 0, stream>>>(ei, E, deg);
    scan1_kernel<<<nb, 256, 0, stream>>>(deg, row, bsums, n);
    scan2_kernel<<<1, 256, 0, stream>>>(bsums, nb);
    scan3_kernel<<<nb, 256, 0, stream>>>(row, bsums, n);
    scatter_kernel<<<eblk, 256, 0, stream>>>(ei, E, row, csr);

    int ablk = (n + 3) / 4;
    agg_kernel<<<ablk, 256, 0, stream>>>(csr, row, asrc, adst, h, bias, out, n);
}